// Round 9
// baseline (130.398 us; speedup 1.0000x reference)
//
#include <hip/hip_runtime.h>

// Problem constants
#define BT_TOTAL (32 * 1024)   // B*T = 32768
#define DIM 512                // D
#define NG 8                   // G groups
#define NK 256                 // K codes per group
#define GD 64                  // group dim
#define QB 256                 // queries per block

#define XQ_ELEMS (BT_TOTAL * DIM)          // 16777216
#define LOSS_OFF XQ_ELEMS                  // 16777216
#define IDX_OFF (XQ_ELEMS + 1)             // 16777217

typedef float f32x16 __attribute__((ext_vector_type(16)));

// ---------------------------------------------------------------------------
// Prep: c_sq[g][k] = sum_d cb[g][k][d]^2 (canonical stride-4 order), zero loss
// ---------------------------------------------------------------------------
__global__ void pq_prep(const float* __restrict__ cb,
                        float* __restrict__ csq,
                        float* __restrict__ loss_slot) {
    int i = blockIdx.x * 256 + threadIdx.x;  // 0 .. 2047
    if (i == 0) *loss_slot = 0.0f;
    if (i < NG * NK) {
        const float* row = cb + (size_t)i * GD;
        float a0 = 0.f, a1 = 0.f, a2 = 0.f, a3 = 0.f;
#pragma unroll
        for (int d = 0; d < GD; d += 4) {
            a0 = fmaf(row[d + 0], row[d + 0], a0);
            a1 = fmaf(row[d + 1], row[d + 1], a1);
            a2 = fmaf(row[d + 2], row[d + 2], a2);
            a3 = fmaf(row[d + 3], row[d + 3], a3);
        }
        csq[i] = (a0 + a1) + (a2 + a3);
    }
}

// ---------------------------------------------------------------------------
// Main: EXACT round-4 structure (hardware-proven: per-iteration s_load
// dwordx16 + tied-operand lgkmcnt(0) wait, no loop-carried asm values,
// no pins). Only deltas vs round 4: amdgpu_waves_per_eu(4,4) to raise the
// RA's VGPR budget to 128 so the 64-float x row stays register-resident,
// and xr held as scalar floats.
// ---------------------------------------------------------------------------
__global__ __launch_bounds__(256)
__attribute__((amdgpu_waves_per_eu(4, 4)))
void pq_main(const float* __restrict__ x,
             const float* __restrict__ cb,
             const float* __restrict__ csq,
             float* __restrict__ out) {
    const int g = blockIdx.y;
    const int t = threadIdx.x;
    const int q0 = blockIdx.x * QB;
    const int bt = q0 + t;

    __shared__ int   m_i[QB];
    __shared__ float wsum[4];

    const float* cbg = cb + (size_t)g * NK * GD;
    const float* csqg = csq + g * NK;

    // x row -> 64 scalar VGPRs (vectorized loads, scalar registers)
    const float* xrow = x + (size_t)bt * DIM + g * GD;
    float xr[64];
#pragma unroll
    for (int i = 0; i < 16; ++i) {
        float4 v = ((const float4*)xrow)[i];
        xr[i * 4 + 0] = v.x;
        xr[i * 4 + 1] = v.y;
        xr[i * 4 + 2] = v.z;
        xr[i * 4 + 3] = v.w;
    }

    // x_sq, canonical stride-4 pattern (bit-matches rounds 1-4)
    float a0 = 0.f, a1 = 0.f, a2 = 0.f, a3 = 0.f;
#pragma unroll
    for (int i = 0; i < 16; ++i) {
        a0 = fmaf(xr[i * 4 + 0], xr[i * 4 + 0], a0);
        a1 = fmaf(xr[i * 4 + 1], xr[i * 4 + 1], a1);
        a2 = fmaf(xr[i * 4 + 2], xr[i * 4 + 2], a2);
        a3 = fmaf(xr[i * 4 + 3], xr[i * 4 + 3], a3);
    }
    const float x_sq = (a0 + a1) + (a2 + a3);

    float best = 3.402823466e38f;
    int bi = 0;

#pragma unroll 1
    for (int k = 0; k < NK; ++k) {
        f32x16 c0, c1, c2, c3;
        float cs;
        const float* ck = cbg + (size_t)k * GD;
        const float* pk = csqg + k;
        // wave-uniform scalar loads: one 256B code row + its c_sq
        asm volatile(
            "s_load_dwordx16 %0, %5, 0x0\n\t"
            "s_load_dwordx16 %1, %5, 0x40\n\t"
            "s_load_dwordx16 %2, %5, 0x80\n\t"
            "s_load_dwordx16 %3, %5, 0xc0\n\t"
            "s_load_dword    %4, %6, 0x0"
            : "=s"(c0), "=s"(c1), "=s"(c2), "=s"(c3), "=s"(cs)
            : "s"(ck), "s"(pk));
        // waitcnt with tied operands (round-4 proven form): uses below depend on it
        asm volatile("s_waitcnt lgkmcnt(0)"
                     : "+s"(c0), "+s"(c1), "+s"(c2), "+s"(c3), "+s"(cs));

        // dot, dims ascending, accumulator = dim%4 (bit-matches rounds 1-4)
        float d0 = 0.f, d1 = 0.f, d2 = 0.f, d3 = 0.f;
#define Q4(cv, i4, b)                                     \
        d0 = fmaf(cv[(i4) * 4 + 0], xr[(b) * 4 + 0], d0); \
        d1 = fmaf(cv[(i4) * 4 + 1], xr[(b) * 4 + 1], d1); \
        d2 = fmaf(cv[(i4) * 4 + 2], xr[(b) * 4 + 2], d2); \
        d3 = fmaf(cv[(i4) * 4 + 3], xr[(b) * 4 + 3], d3);
        Q4(c0, 0, 0)  Q4(c0, 1, 1)  Q4(c0, 2, 2)  Q4(c0, 3, 3)
        Q4(c1, 0, 4)  Q4(c1, 1, 5)  Q4(c1, 2, 6)  Q4(c1, 3, 7)
        Q4(c2, 0, 8)  Q4(c2, 1, 9)  Q4(c2, 2, 10) Q4(c2, 3, 11)
        Q4(c3, 0, 12) Q4(c3, 1, 13) Q4(c3, 2, 14) Q4(c3, 3, 15)
#undef Q4
        float dot = (d0 + d1) + (d2 + d3);
        float dist = (x_sq + cs) - 2.0f * dot;
        if (dist < best) { best = dist; bi = k; }
    }

    m_i[t] = bi;
    out[IDX_OFF + (size_t)bt * NG + g] = (float)bi;
    __syncthreads();

    // ---- epilogue: coalesced x_q writes + loss partial (round-4 pattern) ----
    const int r_off = t >> 4;   // 0..15
    const int c4i = t & 15;     // float4 column
    float s0 = 0.f, s1 = 0.f, s2 = 0.f, s3 = 0.f;
#pragma unroll
    for (int p = 0; p < 16; ++p) {
        const int r = p * 16 + r_off;
        const int code = m_i[r];
        const size_t base = (size_t)(q0 + r) * DIM + g * GD + c4i * 4;
        float4 x4 = *(const float4*)(x + base);
        float4 q4 = *(const float4*)(cbg + (size_t)code * GD + c4i * 4);
        float dx = q4.x - x4.x;
        float dy = q4.y - x4.y;
        float dz = q4.z - x4.z;
        float dw = q4.w - x4.w;
        float4 o;
        o.x = x4.x + dx;
        o.y = x4.y + dy;
        o.z = x4.z + dz;
        o.w = x4.w + dw;
        *(float4*)(out + base) = o;
        s0 = fmaf(dx, dx, s0);
        s1 = fmaf(dy, dy, s1);
        s2 = fmaf(dz, dz, s2);
        s3 = fmaf(dw, dw, s3);
    }
    float part = (s0 + s1) + (s2 + s3);

    // wave reduce (64 lanes)
#pragma unroll
    for (int off = 32; off > 0; off >>= 1) part += __shfl_down(part, off);

    const int lane = t & 63;
    const int wid = t >> 6;
    if (lane == 0) wsum[wid] = part;
    __syncthreads();
    if (t == 0) {
        float bs = (wsum[0] + wsum[1]) + (wsum[2] + wsum[3]);
        // losses = 2 * sum_g mean_{B,T,gd}; divisor = 32768*64 = 2097152
        atomicAdd(out + LOSS_OFF, bs * (2.0f / 2097152.0f));
    }
}

extern "C" void kernel_launch(void* const* d_in, const int* in_sizes, int n_in,
                              void* d_out, int out_size, void* d_ws, size_t ws_size,
                              hipStream_t stream) {
    const float* x = (const float*)d_in[0];
    const float* cb = (const float*)d_in[1];
    float* out = (float*)d_out;
    float* csq = (float*)d_ws;  // 2048 floats = 8 KB scratch

    pq_prep<<<dim3(8), dim3(256), 0, stream>>>(cb, csq, out + LOSS_OFF);

    dim3 grid(BT_TOTAL / QB, NG);   // (128, 8) = 1024 blocks
    pq_main<<<grid, dim3(256), 0, stream>>>(x, cb, csq, out);
}

// Round 10
// 124.854 us; speedup vs baseline: 1.0444x; 1.0444x over previous
//
#include <hip/hip_runtime.h>

// Problem constants
#define BT_TOTAL (32 * 1024)   // B*T = 32768
#define DIM 512                // D
#define NG 8                   // G groups
#define NK 256                 // K codes per group
#define GD 64                  // group dim
#define QB 128                 // queries per block (x2 k-halves = 256 threads)

#define XQ_ELEMS (BT_TOTAL * DIM)          // 16777216
#define LOSS_OFF XQ_ELEMS                  // 16777216
#define IDX_OFF (XQ_ELEMS + 1)             // 16777217

typedef float f32x16 __attribute__((ext_vector_type(16)));

// ---------------------------------------------------------------------------
// Prep: c_sq[g][k] = sum_d cb[g][k][d]^2 (canonical stride-4 order), zero loss
// ---------------------------------------------------------------------------
__global__ void pq_prep(const float* __restrict__ cb,
                        float* __restrict__ csq,
                        float* __restrict__ loss_slot) {
    int i = blockIdx.x * 256 + threadIdx.x;  // 0 .. 2047
    if (i == 0) *loss_slot = 0.0f;
    if (i < NG * NK) {
        const float* row = cb + (size_t)i * GD;
        float a0 = 0.f, a1 = 0.f, a2 = 0.f, a3 = 0.f;
#pragma unroll
        for (int d = 0; d < GD; d += 4) {
            a0 = fmaf(row[d + 0], row[d + 0], a0);
            a1 = fmaf(row[d + 1], row[d + 1], a1);
            a2 = fmaf(row[d + 2], row[d + 2], a2);
            a3 = fmaf(row[d + 3], row[d + 3], a3);
        }
        csq[i] = (a0 + a1) + (a2 + a3);
    }
}

// ---------------------------------------------------------------------------
// Main: 256 threads = 128 queries x 2 k-halves (waves 0,1: k=0..127;
// waves 2,3: k=128..255). Per-thread loop body is the round-9 hardware-proven
// scalar-broadcast form (s_load_dwordx16 x4 + tied lgkmcnt(0), no loop-carried
// asm). LDS merge prefers the lower half on ties = exact ascending first-min.
// Grid doubles to 8192 waves -> 8 waves/SIMD for SMEM latency hiding.
// ---------------------------------------------------------------------------
__global__ __launch_bounds__(256)
void pq_main(const float* __restrict__ x,
             const float* __restrict__ cb,
             const float* __restrict__ csq,
             float* __restrict__ out) {
    const int g = blockIdx.y;
    const int t = threadIdx.x;
    const int kh = __builtin_amdgcn_readfirstlane(t >> 7);  // wave-uniform 0/1
    const int ql = t & (QB - 1);
    const int q0 = blockIdx.x * QB;
    const int bt = q0 + ql;

    __shared__ float m_d[QB];
    __shared__ int   m_i[QB];
    __shared__ float wsum[4];

    const float* cbg = cb + (size_t)g * NK * GD;
    const float* csqg = csq + g * NK;

    // x row -> 64 scalar VGPR values (vectorized loads)
    const float* xrow = x + (size_t)bt * DIM + g * GD;
    float xr[64];
#pragma unroll
    for (int i = 0; i < 16; ++i) {
        float4 v = ((const float4*)xrow)[i];
        xr[i * 4 + 0] = v.x;
        xr[i * 4 + 1] = v.y;
        xr[i * 4 + 2] = v.z;
        xr[i * 4 + 3] = v.w;
    }

    // x_sq, canonical stride-4 pattern (bit-matches rounds 1-9)
    float a0 = 0.f, a1 = 0.f, a2 = 0.f, a3 = 0.f;
#pragma unroll
    for (int i = 0; i < 16; ++i) {
        a0 = fmaf(xr[i * 4 + 0], xr[i * 4 + 0], a0);
        a1 = fmaf(xr[i * 4 + 1], xr[i * 4 + 1], a1);
        a2 = fmaf(xr[i * 4 + 2], xr[i * 4 + 2], a2);
        a3 = fmaf(xr[i * 4 + 3], xr[i * 4 + 3], a3);
    }
    const float x_sq = (a0 + a1) + (a2 + a3);

    const int kbase = kh << 7;  // 0 or 128, wave-uniform
    float best = 3.402823466e38f;
    int bi = kbase;

#pragma unroll 1
    for (int kk = 0; kk < NK / 2; ++kk) {
        const int k = kbase + kk;
        f32x16 c0, c1, c2, c3;
        float cs;
        const float* ck = cbg + (size_t)k * GD;
        const float* pk = csqg + k;
        // wave-uniform scalar loads: one 256B code row + its c_sq
        asm volatile(
            "s_load_dwordx16 %0, %5, 0x0\n\t"
            "s_load_dwordx16 %1, %5, 0x40\n\t"
            "s_load_dwordx16 %2, %5, 0x80\n\t"
            "s_load_dwordx16 %3, %5, 0xc0\n\t"
            "s_load_dword    %4, %6, 0x0"
            : "=s"(c0), "=s"(c1), "=s"(c2), "=s"(c3), "=s"(cs)
            : "s"(ck), "s"(pk));
        // waitcnt with tied operands (round-4/9 proven form)
        asm volatile("s_waitcnt lgkmcnt(0)"
                     : "+s"(c0), "+s"(c1), "+s"(c2), "+s"(c3), "+s"(cs));

        // dot, dims ascending, accumulator = dim%4 (bit-matches rounds 1-9)
        float d0 = 0.f, d1 = 0.f, d2 = 0.f, d3 = 0.f;
#define Q4(cv, i4, b)                                     \
        d0 = fmaf(cv[(i4) * 4 + 0], xr[(b) * 4 + 0], d0); \
        d1 = fmaf(cv[(i4) * 4 + 1], xr[(b) * 4 + 1], d1); \
        d2 = fmaf(cv[(i4) * 4 + 2], xr[(b) * 4 + 2], d2); \
        d3 = fmaf(cv[(i4) * 4 + 3], xr[(b) * 4 + 3], d3);
        Q4(c0, 0, 0)  Q4(c0, 1, 1)  Q4(c0, 2, 2)  Q4(c0, 3, 3)
        Q4(c1, 0, 4)  Q4(c1, 1, 5)  Q4(c1, 2, 6)  Q4(c1, 3, 7)
        Q4(c2, 0, 8)  Q4(c2, 1, 9)  Q4(c2, 2, 10) Q4(c2, 3, 11)
        Q4(c3, 0, 12) Q4(c3, 1, 13) Q4(c3, 2, 14) Q4(c3, 3, 15)
#undef Q4
        float dot = (d0 + d1) + (d2 + d3);
        float dist = (x_sq + cs) - 2.0f * dot;
        if (dist < best) { best = dist; bi = k; }
    }

    // merge the two halves: prefer the lower half on exact ties
    if (kh == 1) { m_d[ql] = best; m_i[ql] = bi; }
    __syncthreads();
    if (kh == 0) {
        float dh = m_d[ql];
        int ih = m_i[ql];
        if (dh < best) { best = dh; bi = ih; }
        m_i[ql] = bi;  // final winner for the epilogue
        out[IDX_OFF + (size_t)bt * NG + g] = (float)bi;
    }
    __syncthreads();

    // ---- epilogue: coalesced x_q writes + loss partial (round-2 pattern) ----
    const int r_off = t >> 4;   // 0..15
    const int c4i = t & 15;     // float4 column
    float s0 = 0.f, s1 = 0.f, s2 = 0.f, s3 = 0.f;
#pragma unroll
    for (int p = 0; p < 8; ++p) {
        const int r = p * 16 + r_off;
        const int code = m_i[r];
        const size_t base = (size_t)(q0 + r) * DIM + g * GD + c4i * 4;
        float4 x4 = *(const float4*)(x + base);
        float4 q4 = *(const float4*)(cbg + (size_t)code * GD + c4i * 4);
        float dx = q4.x - x4.x;
        float dy = q4.y - x4.y;
        float dz = q4.z - x4.z;
        float dw = q4.w - x4.w;
        float4 o;
        o.x = x4.x + dx;
        o.y = x4.y + dy;
        o.z = x4.z + dz;
        o.w = x4.w + dw;
        *(float4*)(out + base) = o;
        s0 = fmaf(dx, dx, s0);
        s1 = fmaf(dy, dy, s1);
        s2 = fmaf(dz, dz, s2);
        s3 = fmaf(dw, dw, s3);
    }
    float part = (s0 + s1) + (s2 + s3);

    // wave reduce (64 lanes)
#pragma unroll
    for (int off = 32; off > 0; off >>= 1) part += __shfl_down(part, off);

    const int lane = t & 63;
    const int wid = t >> 6;
    if (lane == 0) wsum[wid] = part;
    __syncthreads();
    if (t == 0) {
        float bs = (wsum[0] + wsum[1]) + (wsum[2] + wsum[3]);
        // losses = 2 * sum_g mean_{B,T,gd}; divisor = 32768*64 = 2097152
        atomicAdd(out + LOSS_OFF, bs * (2.0f / 2097152.0f));
    }
}

extern "C" void kernel_launch(void* const* d_in, const int* in_sizes, int n_in,
                              void* d_out, int out_size, void* d_ws, size_t ws_size,
                              hipStream_t stream) {
    const float* x = (const float*)d_in[0];
    const float* cb = (const float*)d_in[1];
    float* out = (float*)d_out;
    float* csq = (float*)d_ws;  // 2048 floats = 8 KB scratch

    pq_prep<<<dim3(8), dim3(256), 0, stream>>>(cb, csq, out + LOSS_OFF);

    dim3 grid(BT_TOTAL / QB, NG);   // (256, 8) = 2048 blocks, 8192 waves
    pq_main<<<grid, dim3(256), 0, stream>>>(x, cb, csq, out);
}